// Round 1
// baseline (2623.220 us; speedup 1.0000x reference)
//
#include <hip/hip_runtime.h>
#include <cstdint>
#include <cstddef>

typedef unsigned short u16;
typedef unsigned char u8;
typedef unsigned int u32;

typedef short s16x8 __attribute__((ext_vector_type(8)));
typedef float f32x4 __attribute__((ext_vector_type(4)));

// ---------------- helpers ----------------
__device__ __forceinline__ float b2f(u16 h){ u32 u = ((u32)h)<<16; float f; __builtin_memcpy(&f,&u,4); return f; }
__device__ __forceinline__ u16 f2b(float x){ u32 u; __builtin_memcpy(&u,&x,4); u += 0x7fffu + ((u>>16)&1u); return (u16)(u>>16); }
__device__ __forceinline__ float sigf(float x){ return 1.f/(1.f+__expf(-x)); }
__device__ __forceinline__ float tanh2(float x){
  float ax=fabsf(x); float e=__expf(-2.f*ax); float r=(1.f-e)/(1.f+e); return x<0.f? -r : r;
}

typedef __attribute__((address_space(1))) const void gvoid_t;
typedef __attribute__((address_space(3))) void lvoid_t;
__device__ __forceinline__ void gl_lds16(const u16* src, u16* dst){
  __builtin_amdgcn_global_load_lds((gvoid_t*)src, (lvoid_t*)dst, 16, 0, 0);
}

// ---------------- mask dtype detection + canonicalization ----------------
__global__ void detect_mask_mode(const u8* raw, int n, int* flag){
  __shared__ int cnt;
  int tid = threadIdx.x;
  if(tid==0) cnt=0;
  __syncthreads();
  int c=0;
  for(int i=tid;i<n;i+=blockDim.x) c += (raw[i]!=0);
  atomicAdd(&cnt, c);
  __syncthreads();
  if(tid==0) *flag = (cnt > (n>>2)) ? 1 : 0;  // 1 => byte-per-element layout
}

__global__ void convert_masks(const void* done_raw, const void* main_raw, u8* done_u8, u8* main_u8, int n, const int* flag){
  int mode = *flag;
  for(int i = blockIdx.x*blockDim.x + threadIdx.x; i<n; i += gridDim.x*blockDim.x){
    u8 d, m;
    if(mode){ d = ((const u8*)done_raw)[i]!=0; m = ((const u8*)main_raw)[i]!=0; }
    else    { d = ((const int*)done_raw)[i]!=0; m = ((const int*)main_raw)[i]!=0; }
    done_u8[i]=d; main_u8[i]=m;
  }
}

// ---------------- conversions ----------------
__global__ void cvt_f32_bf16(const float* __restrict__ in, u16* __restrict__ out, int n4){
  int i = blockIdx.x*blockDim.x + threadIdx.x;
  if(i < n4){
    float4 v = ((const float4*)in)[i];
    ushort4 o;
    o.x=f2b(v.x); o.y=f2b(v.y); o.z=f2b(v.z); o.w=f2b(v.w);
    ((ushort4*)out)[i]=o;
  }
}

// in [R][C] f32  ->  out [C][R] bf16
__global__ void transpose_to_bf16(const float* __restrict__ in, u16* __restrict__ out, int R, int C){
  __shared__ float tile[64][65];
  int c0 = blockIdx.x*64, r0 = blockIdx.y*64;
  int tx = threadIdx.x & 63, ty = threadIdx.x >> 6;   // 256 threads
  for(int i=ty;i<64;i+=4) tile[i][tx] = in[(size_t)(r0+i)*C + c0 + tx];
  __syncthreads();
  for(int i=ty;i<64;i+=4) out[(size_t)(c0+i)*R + r0 + tx] = f2b(tile[tx][i]);
}

__global__ void init_states(const float* __restrict__ c1in, const float* __restrict__ h1in,
                            const float* __restrict__ c2in, const float* __restrict__ h2in,
                            const u8* __restrict__ mmain,
                            float* __restrict__ c1, float* __restrict__ c2,
                            u16* __restrict__ h1, u16* __restrict__ h2, u16* __restrict__ hsel0){
  int i = blockIdx.x*blockDim.x + threadIdx.x;
  if(i < 256*1024){
    int row = i >> 10;
    c1[i]=c1in[i]; c2[i]=c2in[i];
    u16 a=f2b(h1in[i]), b=f2b(h2in[i]);
    h1[i]=a; h2[i]=b;
    hsel0[i] = mmain[row] ? a : b;
  }
}

// ---------------- phase 1: Zx = x @ Wi + b  (m97-style 128x128 tile) ----------------
// A: [M][K] bf16 row-major; Bt: [N][K] bf16 row-major (Wi transposed); out [M][N]
template<bool ZF32>
__global__ __launch_bounds__(256) void gemm_zx(const u16* __restrict__ A, const u16* __restrict__ Bt,
                                               const float* __restrict__ bias, void* __restrict__ Cout,
                                               int M, int N, int K){
  __shared__ u16 As[128*32];
  __shared__ u16 Bs[128*32];
  int nbx = N>>7, nby = M>>7;
  int nwg = nbx*nby;                 // 8192, divisible by 8
  int gid = blockIdx.x;
  int per = nwg>>3;
  int g2 = (gid&7)*per + (gid>>3);   // XCD-contiguous remap (bijective: nwg%8==0)
  int tpg = 8*nbx;                   // 8-row supergroup x all cols
  int grp = g2/tpg, w = g2%tpg;
  int brow = grp*8 + (w & 7);
  int bcol = w >> 3;
  int row0 = brow<<7, col0 = bcol<<7;

  int tid=threadIdx.x, wid=tid>>6, lane=tid&63;
  int l15=lane&15, hi=lane>>4;
  int wm=(wid>>1)<<6, wn=(wid&1)<<6;

  f32x4 acc[4][4];
  #pragma unroll
  for(int m=0;m<4;m++)
    #pragma unroll
    for(int n=0;n<4;n++) acc[m][n]=(f32x4){0.f,0.f,0.f,0.f};

  for(int k0=0;k0<K;k0+=32){
    __syncthreads();                 // prior reads done before overwrite
    #pragma unroll
    for(int q=0;q<2;q++){
      int cb=q*256+wid*64;
      int ch=cb+lane;
      gl_lds16(A + (size_t)(row0+(ch>>2))*K + k0 + (ch&3)*8, &As[cb*8]);
    }
    #pragma unroll
    for(int q=0;q<2;q++){
      int cb=q*256+wid*64;
      int ch=cb+lane;
      gl_lds16(Bt + (size_t)(col0+(ch>>2))*K + k0 + (ch&3)*8, &Bs[cb*8]);
    }
    __syncthreads();                 // vmcnt(0) drain + barrier
    s16x8 a[4], b[4];
    #pragma unroll
    for(int m=0;m<4;m++) a[m] = *(const s16x8*)&As[(wm+m*16+l15)*32 + hi*8];
    #pragma unroll
    for(int n=0;n<4;n++) b[n] = *(const s16x8*)&Bs[(wn+n*16+l15)*32 + hi*8];
    #pragma unroll
    for(int m=0;m<4;m++)
      #pragma unroll
      for(int n=0;n<4;n++)
        acc[m][n] = __builtin_amdgcn_mfma_f32_16x16x32_bf16(a[m],b[n],acc[m][n],0,0,0);
  }
  #pragma unroll
  for(int m=0;m<4;m++){
    #pragma unroll
    for(int n=0;n<4;n++){
      #pragma unroll
      for(int j=0;j<4;j++){
        int r = row0+wm+m*16+hi*4+j;
        int c = col0+wn+n*16+l15;
        float v = acc[m][n][j] + bias[c];
        if(ZF32) ((float*)Cout)[(size_t)r*N+c]=v;
        else     ((u16*)Cout)[(size_t)r*N+c]=f2b(v);
      }
    }
  }
}

// ---------------- phase 2: one recurrent step, fully fused ----------------
// grid = 256 blocks: bid&3 = row-group (64 rows), bid>>2 = jj-group (16 cols of H).
// Wave g computes gate g for its 64x16 tile. LDS rows are 128B => XOR-swizzle slot^(row&7)
// applied on global_load_lds SOURCE and on ds_read address (both-sides involution).
template<bool ZF32>
__global__ __launch_bounds__(256) void lstm_step(const void* __restrict__ Zx, const u16* __restrict__ Wht,
     const u16* __restrict__ hin, u16* __restrict__ hout,
     float* __restrict__ c1, float* __restrict__ c2, u16* __restrict__ h1, u16* __restrict__ h2,
     const u8* __restrict__ mdone, const u8* __restrict__ mmain,
     float* __restrict__ out, int t){
  __shared__ u16 As[64*64];        // h tile  [64 rows][64 k]
  __shared__ u16 Bs[4][16*64];     // per-gate Wh^T tile [16 n][64 k]
  __shared__ float zb[4][64*17];   // gate outputs for epilogue exchange

  int bid=blockIdx.x;
  int rg=bid&3, jg=bid>>2;
  int r0=rg<<6, j0=jg<<4;
  int tid=threadIdx.x, wid=tid>>6, lane=tid&63;
  int l15=lane&15, hi=lane>>4;

  f32x4 acc[4];
  #pragma unroll
  for(int m=0;m<4;m++) acc[m]=(f32x4){0.f,0.f,0.f,0.f};

  for(int k0=0;k0<1024;k0+=64){
    __syncthreads();
    #pragma unroll
    for(int q=0;q<2;q++){           // A: 8KB = 512 chunks; wave w: chunks w*128+q*64+lane
      int cb=wid*128+q*64;
      int ch=cb+lane;
      int r=ch>>3, p=ch&7;
      int l = p ^ (r&7);            // pre-swizzled source slot
      gl_lds16(hin + (size_t)(r0+r)*1024 + k0 + l*8, &As[cb*8]);
    }
    #pragma unroll
    for(int q=0;q<2;q++){           // B: wave w stages gate w's 2KB = 128 chunks
      int cb=q*64;
      int ch=cb+lane;
      int r=ch>>3, p=ch&7;
      int l = p ^ (r&7);
      gl_lds16(Wht + (size_t)(wid*1024 + j0 + r)*1024 + k0 + l*8, &Bs[wid][cb*8]);
    }
    __syncthreads();
    #pragma unroll
    for(int ks=0;ks<2;ks++){
      int slot = ks*4 + hi;
      s16x8 b = *(const s16x8*)&Bs[wid][ l15*64 + ((slot ^ (l15&7))*8) ];
      #pragma unroll
      for(int m=0;m<4;m++){
        int ar = m*16 + l15;
        s16x8 a = *(const s16x8*)&As[ ar*64 + ((slot ^ (ar&7))*8) ];
        acc[m] = __builtin_amdgcn_mfma_f32_16x16x32_bf16(a,b,acc[m],0,0,0);
      }
    }
  }
  // exchange gate results through LDS
  #pragma unroll
  for(int m=0;m<4;m++){
    #pragma unroll
    for(int j=0;j<4;j++){
      int rr=m*16+hi*4+j;
      zb[wid][rr*17 + l15] = acc[m][j];
    }
  }
  __syncthreads();

  const u16* Zb = (const u16*)Zx;
  const float* Zf = (const float*)Zx;
  #pragma unroll
  for(int e=0;e<4;e++){
    int idx=e*256+tid;
    int row=idx>>4, col=idx&15;
    int grow=r0+row;
    int gb=t*256+grow;
    int gcol=j0+col;
    size_t zoff=(size_t)gb*4096 + gcol;
    float zi,zf,zg,zo;
    if(ZF32){ zi=Zf[zoff]; zf=Zf[zoff+1024]; zg=Zf[zoff+2048]; zo=Zf[zoff+3072]; }
    else    { zi=b2f(Zb[zoff]); zf=b2f(Zb[zoff+1024]); zg=b2f(Zb[zoff+2048]); zo=b2f(Zb[zoff+3072]); }
    int li=row*17+col;
    zi += zb[0][li]; zf += zb[1][li]; zg += zb[2][li]; zo += zb[3][li];

    bool mm = mmain[gb]!=0, dd = mdone[gb]!=0;
    size_t sidx=(size_t)grow*1024 + gcol;
    float c1o=c1[sidx], c2o=c2[sidx];
    float co = mm ? c1o : c2o;
    float nc = sigf(zf)*co + sigf(zi)*tanh2(zg);
    float nh = sigf(zo)*tanh2(nc);
    out[(size_t)gb*1024+gcol]=nh;

    u16 h1o=h1[sidx], h2o=h2[sidx];
    u16 nhb=f2b(nh);
    float n1c = mm?nc:c1o, n2c = mm?c2o:nc;
    u16  n1h = mm?nhb:h1o, n2h = mm?h2o:nhb;
    if(dd){ n1c=0.f; n2c=0.f; n1h=0; n2h=0; }
    c1[sidx]=n1c; c2[sidx]=n2c; h1[sidx]=n1h; h2[sidx]=n2h;
    if(t<127){
      bool m2 = mmain[gb+256]!=0;
      hout[sidx] = m2 ? n1h : n2h;
    }
  }
}

// ---------------- host ----------------
extern "C" void kernel_launch(void* const* d_in, const int* in_sizes, int n_in,
                              void* d_out, int out_size, void* d_ws, size_t ws_size,
                              hipStream_t stream){
  const float* x   = (const float*)d_in[0];
  const float* c1i = (const float*)d_in[1];
  const float* h1i = (const float*)d_in[2];
  const float* c2i = (const float*)d_in[3];
  const float* h2i = (const float*)d_in[4];
  const float* Wi  = (const float*)d_in[5];
  const float* Wh  = (const float*)d_in[6];
  const float* bias= (const float*)d_in[7];
  const void* done_raw = d_in[8];
  const void* main_raw = d_in[9];
  float* out = (float*)d_out;

  char* ws = (char*)d_ws;
  size_t off=0;
  auto alloc=[&](size_t sz)->char*{ char* p = ws+off; off += (sz+255)&~(size_t)255; return p; };

  u16* xb   = (u16*)alloc(33554432ull*2);        // x as bf16 [32768][1024]
  u16* WiT  = (u16*)alloc(4096ull*1024*2);       // Wi^T bf16 [4096][1024]
  u16* WhT  = (u16*)alloc(4096ull*1024*2);       // Wh^T bf16 [4096][1024]
  float* c1 = (float*)alloc(262144ull*4);
  float* c2 = (float*)alloc(262144ull*4);
  u16* h1   = (u16*)alloc(262144ull*2);
  u16* h2   = (u16*)alloc(262144ull*2);
  u16* hs0  = (u16*)alloc(262144ull*2);
  u16* hs1  = (u16*)alloc(262144ull*2);
  u8* dmask = (u8*)alloc(32768);
  u8* mmask = (u8*)alloc(32768);
  int* flag = (int*)alloc(256);

  bool zf32 = (off + 536870912ull) <= ws_size;   // Zx fp32 if workspace allows
  void* Zx  = (void*)alloc(zf32 ? 536870912ull : 268435456ull);

  detect_mask_mode<<<1,256,0,stream>>>((const u8*)done_raw, 32768, flag);
  convert_masks<<<64,256,0,stream>>>(done_raw, main_raw, dmask, mmask, 32768, flag);
  cvt_f32_bf16<<<32768,256,0,stream>>>(x, xb, 8388608);
  transpose_to_bf16<<<dim3(64,16),256,0,stream>>>(Wi, WiT, 1024, 4096);
  transpose_to_bf16<<<dim3(64,16),256,0,stream>>>(Wh, WhT, 1024, 4096);
  init_states<<<1024,256,0,stream>>>(c1i,h1i,c2i,h2i,mmask,c1,c2,h1,h2,hs0);

  if(zf32) gemm_zx<true ><<<8192,256,0,stream>>>(xb, WiT, bias, Zx, 32768, 4096, 1024);
  else     gemm_zx<false><<<8192,256,0,stream>>>(xb, WiT, bias, Zx, 32768, 4096, 1024);

  u16* hbuf[2]={hs0,hs1};
  for(int t=0;t<128;t++){
    const u16* hi_ = hbuf[t&1];
    u16* ho_ = hbuf[(t+1)&1];
    if(zf32) lstm_step<true ><<<256,256,0,stream>>>(Zx,WhT,hi_,ho_,c1,c2,h1,h2,dmask,mmask,out,t);
    else     lstm_step<false><<<256,256,0,stream>>>(Zx,WhT,hi_,ho_,c1,c2,h1,h2,dmask,mmask,out,t);
  }
}